// Round 9
// baseline (139.955 us; speedup 1.0000x reference)
//
#include <hip/hip_runtime.h>
#include <math.h>

#define NW   12
#define DIM  4096
#define TPB  256

typedef float v2f __attribute__((ext_vector_type(2)));   // (re, im) -> v_pk_* f32

// DPP lane exchange (VALU, no LDS pipe).
// 0xB1=quad XOR1, 0x4E=quad XOR2, 0x1B=quad XOR3, 0x128=row_ror:8 (XOR8), 0x141=row_half_mirror (XOR7).
template<int CTRL>
__device__ __forceinline__ float fdpp(float v) {
    union { float f; int i; } u, w;
    u.f = v;
    w.i = __builtin_amdgcn_update_dpp(0, u.i, CTRL, 0xF, 0xF, false);
    return w.f;
}

__device__ __forceinline__ v2f cmulq(v2f a, v2f b) {
    return (v2f){ fmaf(a.x, b.x, -a.y * b.y), fmaf(a.x, b.y, a.y * b.x) };
}

// RY on register bit B (0..3 of the 16-amp register file). Packed-f32 VALU.
template<int B>
__device__ __forceinline__ void ry_reg(v2f* r, float c, v2f vps, v2f vms) {
#pragma unroll
    for (int p = 0; p < 8; ++p) {
        const int i0 = ((p >> B) << (B + 1)) | (p & ((1 << B) - 1));
        const int i1 = i0 | (1 << B);
        const v2f a = r[i0], b = r[i1];
        r[i0] = __builtin_elementwise_fma(vms, b, a * c);   // c*a - s*b
        r[i1] = __builtin_elementwise_fma(vps, a, b * c);   // s*a + c*b
    }
}

// RY via single-DPP partner exchange on a lane bit.
template<int CTRL>
__device__ __forceinline__ void ry_dpp(v2f* r, float c, v2f vsp) {
#pragma unroll
    for (int k = 0; k < 16; ++k) {
        const v2f p = { fdpp<CTRL>(r[k].x), fdpp<CTRL>(r[k].y) };
        r[k] = __builtin_elementwise_fma(vsp, p, r[k] * c);
    }
}

// RY on lane bit 2 (XOR4): partner = half_mirror(quad_xor3(x)) -> x[l^7^3] = x[l^4].
__device__ __forceinline__ void ry_xor4(v2f* r, float c, v2f vsp) {
#pragma unroll
    for (int k = 0; k < 16; ++k) {
        const v2f p = { fdpp<0x141>(fdpp<0x1B>(r[k].x)),
                        fdpp<0x141>(fdpp<0x1B>(r[k].y)) };
        r[k] = __builtin_elementwise_fma(vsp, p, r[k] * c);
    }
}

// Measure fold (round-8-verified): state in L1 layout, amp u = t0-3 | k<<4 | t4-7<<8,
// pre-CNOT; psi_post[v] = phi[v^(v>>1)] => <Z_w> sign = parity(u >> (11-w)).
__device__ __forceinline__ void measure12(const v2f* r, int tid, float* contrib) {
    float T = 0.f, Sp = 0.f, Sa = 0.f, Sb = 0.f, Sc = 0.f;
#pragma unroll
    for (int k = 0; k < 16; ++k) {
        const float pp = fmaf(r[k].x, r[k].x, r[k].y * r[k].y);
        T += pp;
        Sp += (__popc(k) & 1)      ? -pp : pp;
        Sa += (__popc(k >> 1) & 1) ? -pp : pp;
        Sb += (__popc(k >> 2) & 1) ? -pp : pp;
        Sc += ((k >> 3) & 1)       ? -pp : pp;
    }
    const int t1 = (tid >> 1) & 1, t2 = (tid >> 2) & 1, t3 = (tid >> 3) & 1;
    const int t4 = (tid >> 4) & 1, t5 = (tid >> 5) & 1, t6 = (tid >> 6) & 1,
              t7 = (tid >> 7) & 1;
    const int p47 = t4 ^ t5 ^ t6 ^ t7;
    contrib[0]  = t7                   ? -T : T;
    contrib[1]  = (t6 ^ t7)            ? -T : T;
    contrib[2]  = (t5 ^ t6 ^ t7)       ? -T : T;
    contrib[3]  = p47                  ? -T : T;
    contrib[4]  = p47                  ? -Sc : Sc;
    contrib[5]  = p47                  ? -Sb : Sb;
    contrib[6]  = p47                  ? -Sa : Sa;
    contrib[7]  = p47                  ? -Sp : Sp;
    contrib[8]  = (t3 ^ p47)           ? -Sp : Sp;
    contrib[9]  = (t2 ^ t3 ^ p47)      ? -Sp : Sp;
    contrib[10] = (t1 ^ t2 ^ t3 ^ p47) ? -Sp : Sp;
    contrib[11] = (__popc(tid) & 1)    ? -Sp : Sp;
}

// RT pieces (identity slot map, all base+imm, slot low4 = rank-4 lane bits):
#define PW1(r) _Pragma("unroll") for (int k = 0; k < 16; ++k) psi[(k << 8) | tid] = (r)[k];
#define PR1(r) _Pragma("unroll") for (int k = 0; k < 16; ++k) (r)[k] = psi[base_r | (k << 4)];
#define PW2(r) _Pragma("unroll") for (int k = 0; k < 16; ++k) psi[base_r | (k << 4)] = (r)[k];
#define PR2(r) _Pragma("unroll") for (int k = 0; k < 16; ++k) { \
        const int gk = (k ^ (k >> 1)) & 15; \
        (r)[k] = psi[(gt ^ ((k & 1) << 7)) | (gk << 8)]; }
#define RZF(r) _Pragma("unroll") for (int k = 0; k < 16; ++k) { \
        const int j = __popc(k); (r)[k] = cmulq((r)[k], qv[j]); }
#define GREG(r) { ry_reg<0>(r, c, vps, vms); ry_reg<1>(r, c, vps, vms); \
                  ry_reg<2>(r, c, vps, vms); ry_reg<3>(r, c, vps, vms); }
#define GDPP(r) { ry_dpp<0xB1>(r, c, vs0); ry_dpp<0x4E>(r, c, vs1); \
                  ry_xor4(r, c, vs2);      ry_dpp<0x128>(r, c, vs3); }

__global__ __launch_bounds__(TPB, 4)
void qmnist_kernel(const float* __restrict__ x,  const float* __restrict__ W1,
                   const float* __restrict__ b1, const float* __restrict__ ryp,
                   const float* __restrict__ rzp, const float* __restrict__ W2,
                   const float* __restrict__ b2, float* __restrict__ out) {
    // Exactly 32 KiB LDS; small arrays alias the front (barriers order reuse).
    __shared__ v2f psi[DIM];
    float* smf  = (float*)psi;
    float* wred = smf;        // 96 floats (4 waves x 24)
    float* encc = smf + 96;   // 24 (12 per sample)
    float* encs = smf + 120;  // 24
    float* zfin = smf + 144;  // 24

    const int tid  = threadIdx.x;
    const int blk  = blockIdx.x;
    const int lane = tid & 63;
    const int wave = tid >> 6;

    // ---------------- phase 0: TWO samples' encodings; W1 loads shared.
    float acc[2 * NW];
#pragma unroll
    for (int j = 0; j < 2 * NW; ++j) acc[j] = 0.f;
    if (tid < 196) {                      // 784 = 196 float4
        const float4 xv0 = ((const float4*)(x + (size_t)(2 * blk)     * 784))[tid];
        const float4 xv1 = ((const float4*)(x + (size_t)(2 * blk + 1) * 784))[tid];
#pragma unroll
        for (int w = 0; w < NW; ++w) {
            const float4 wv = ((const float4*)(W1 + w * 784))[tid];
            acc[w]      = fmaf(xv0.x, wv.x, fmaf(xv0.y, wv.y, fmaf(xv0.z, wv.z, xv0.w * wv.w)));
            acc[NW + w] = fmaf(xv1.x, wv.x, fmaf(xv1.y, wv.y, fmaf(xv1.z, wv.z, xv1.w * wv.w)));
        }
    }
#pragma unroll
    for (int j = 0; j < 2 * NW; ++j) {
        float v = acc[j];
        v += __shfl_down(v, 32);
        v += __shfl_down(v, 16);
        v += __shfl_down(v, 8);
        v += __shfl_down(v, 4);
        v += __shfl_down(v, 2);
        v += __shfl_down(v, 1);
        if (lane == 0) wred[wave * 24 + j] = v;
    }
    __syncthreads();
    if (tid < 2 * NW) {
        const int w = (tid >= NW) ? tid - NW : tid;
        float feat = wred[tid] + wred[24 + tid] + wred[48 + tid] + wred[72 + tid] + b1[w];
        float a = tanhf(feat) * 3.14159265358979323846f;
        float h = 0.5f * a;
        encc[tid] = cosf(h);
        encs[tid] = sinf(h);
    }
    __syncthreads();

    // ---------------- init both product states into REGISTERS.
    float hiA = 1.f, hiB = 1.f;
#pragma unroll
    for (int b = 0; b < 8; ++b) {
        const int w = 11 - b;
        const bool o = (tid >> b) & 1;
        hiA *= o ? encs[w]      : encc[w];
        hiB *= o ? encs[NW + w] : encc[NW + w];
    }
    v2f rA[16], rB[16];
#pragma unroll
    for (int k = 0; k < 16; ++k) {
        float fA = hiA, fB = hiB;
        fA *= (k & 1) ? encs[3] : encc[3];   fB *= (k & 1) ? encs[NW + 3] : encc[NW + 3];
        fA *= (k & 2) ? encs[2] : encc[2];   fB *= (k & 2) ? encs[NW + 2] : encc[NW + 2];
        fA *= (k & 4) ? encs[1] : encc[1];   fB *= (k & 4) ? encs[NW + 1] : encc[NW + 1];
        fA *= (k & 8) ? encs[0] : encc[0];   fB *= (k & 8) ? encs[NW + 0] : encc[NW + 0];
        rA[k] = (v2f){ fA, 0.f };
        rB[k] = (v2f){ fB, 0.f };
    }

    // ---------------- shared variational params
    const float ry = ryp[0], rz = rzp[0];
    const float c = cosf(0.5f * ry), s = sinf(0.5f * ry);
    const v2f vps = {  s,  s };
    const v2f vms = { -s, -s };
    const int pcT = __popc(tid);
    // qv[j] = cis(rz*(pcT + j - 6)) via 2 sincos + complex recurrence
    v2f qv[5];
    {
        float sb, cb; __sincosf(rz * (float)(pcT - 6), &sb, &cb);
        float sd, cd; __sincosf(rz, &sd, &cd);
        qv[0] = (v2f){ cb, sb };
        const v2f step = (v2f){ cd, sd };
#pragma unroll
        for (int j = 1; j < 5; ++j) qv[j] = cmulq(qv[j - 1], step);
    }
    const v2f vs0 = (lane & 1) ? vps : vms;   // position 0, XOR1  quad_perm
    const v2f vs1 = (lane & 2) ? vps : vms;   // position 1, XOR2  quad_perm
    const v2f vs2 = (lane & 4) ? vps : vms;   // position 2, XOR4  chained DPP
    const v2f vs3 = (lane & 8) ? vps : vms;   // position 3, XOR8  row_ror:8
    const int base_r = (tid & 15) | ((tid & 240) << 4);  // L1 read/write base
    const int gt     = tid ^ (tid >> 1);                 // CNOT Gray base

    // ---------------- 2-sample software pipeline.
    // Per layer & sample: GREG(8-11)+GDPP(0-3) [bufferless] then
    // W1,bar,R1,GREG(4-7),RZF,W2,bar,R2 [buffered]. While one sample owns the
    // buffer, the other runs its bufferless gates -> barrier windows filled.
    GREG(rA); GDPP(rA);                 // A layer-0 bufferless gates
    __syncthreads();                    // enc/psi front reads done
    for (int layer = 0; layer < 2; ++layer) {
        // ---- A buffered phase (layer)
        PW1(rA); GREG(rB);              // B bufferless (this layer)
        __syncthreads();
        PR1(rA); GDPP(rB);
        GREG(rA); RZF(rA);
        PW2(rA);                        // same-slot trick: no barrier after PR1
        __syncthreads();
        PR2(rA);
        __syncthreads();
        // ---- B buffered phase (layer)
        PW1(rB); GREG(rA);              // A bufferless (next layer)
        __syncthreads();
        PR1(rB); GDPP(rA);
        GREG(rB); RZF(rB);
        PW2(rB);
        __syncthreads();
        PR2(rB);
        __syncthreads();
    }
    // ---- final layer (no RZ, no RT-2: folded into measurement)
    PW1(rA); GREG(rB);                  // B final bufferless gates
    __syncthreads();
    PR1(rA); GDPP(rB);
    GREG(rA);                           // A final state (L1 layout)
    __syncthreads();
    float cA[NW], cB[NW];
    PW1(rB); measure12(rA, tid, cA);    // measure A fills B's write window
    __syncthreads();
    PR1(rB);
    GREG(rB);                           // B final state (L1 layout)
    __syncthreads();                    // all psi reads done -> alias reuse OK
    measure12(rB, tid, cB);

    // ---------------- reductions for both samples
#pragma unroll
    for (int w = 0; w < NW; ++w) {
        float va = cA[w], vb = cB[w];
        va += __shfl_down(va, 32);  vb += __shfl_down(vb, 32);
        va += __shfl_down(va, 16);  vb += __shfl_down(vb, 16);
        va += __shfl_down(va, 8);   vb += __shfl_down(vb, 8);
        va += __shfl_down(va, 4);   vb += __shfl_down(vb, 4);
        va += __shfl_down(va, 2);   vb += __shfl_down(vb, 2);
        va += __shfl_down(va, 1);   vb += __shfl_down(vb, 1);
        if (lane == 0) {
            wred[wave * NW + w]      = va;
            wred[48 + wave * NW + w] = vb;
        }
    }
    __syncthreads();
    if (tid < 2 * NW) {
        const int sm = (tid >= NW) ? 1 : 0;
        const int w  = tid - sm * NW;
        zfin[tid] = wred[48 * sm + w] + wred[48 * sm + NW + w]
                  + wred[48 * sm + 2 * NW + w] + wred[48 * sm + 3 * NW + w];
    }
    __syncthreads();

    // ---------------- head: two output rows, two waves in parallel
    if (tid < 10) {
        float o = b2[tid];
#pragma unroll
        for (int w = 0; w < NW; ++w)
            o = fmaf(zfin[w], W2[tid * NW + w], o);
        out[(size_t)(2 * blk) * 10 + tid] = o;
    } else if (tid >= 64 && tid < 74) {
        const int q = tid - 64;
        float o = b2[q];
#pragma unroll
        for (int w = 0; w < NW; ++w)
            o = fmaf(zfin[NW + w], W2[q * NW + w], o);
        out[(size_t)(2 * blk + 1) * 10 + q] = o;
    }
}

extern "C" void kernel_launch(void* const* d_in, const int* in_sizes, int n_in,
                              void* d_out, int out_size, void* d_ws, size_t ws_size,
                              hipStream_t stream) {
    const float* x   = (const float*)d_in[0];
    const float* W1  = (const float*)d_in[1];
    const float* b1  = (const float*)d_in[2];
    const float* ry  = (const float*)d_in[3];
    const float* rz  = (const float*)d_in[4];
    const float* W2  = (const float*)d_in[5];
    const float* b2  = (const float*)d_in[6];
    float* out = (float*)d_out;

    const int batch = in_sizes[0] / 784;   // 2048
    qmnist_kernel<<<batch / 2, TPB, 0, stream>>>(x, W1, b1, ry, rz, W2, b2, out);
}

// Round 12
// 113.781 us; speedup vs baseline: 1.2300x; 1.2300x over previous
//
#include <hip/hip_runtime.h>
#include <math.h>

#define NW   12
#define DIM  4096
#define TPB  256

typedef float v2f __attribute__((ext_vector_type(2)));   // (re, im) -> v_pk_* f32

// DPP lane exchange (VALU, no LDS pipe).
// 0xB1=quad XOR1, 0x4E=quad XOR2, 0x1B=quad XOR3, 0x128=row_ror:8 (XOR8), 0x141=row_half_mirror (XOR7).
template<int CTRL>
__device__ __forceinline__ float fdpp(float v) {
    union { float f; int i; } u, w;
    u.f = v;
    w.i = __builtin_amdgcn_update_dpp(0, u.i, CTRL, 0xF, 0xF, false);
    return w.f;
}

__device__ __forceinline__ v2f cmulq(v2f a, v2f b) {
    return (v2f){ fmaf(a.x, b.x, -a.y * b.y), fmaf(a.x, b.y, a.y * b.x) };
}

// RY on register bit B (0..3 of the 16-amp register file). Packed-f32 VALU.
template<int B>
__device__ __forceinline__ void ry_reg(v2f* r, float c, v2f vps, v2f vms) {
#pragma unroll
    for (int p = 0; p < 8; ++p) {
        const int i0 = ((p >> B) << (B + 1)) | (p & ((1 << B) - 1));
        const int i1 = i0 | (1 << B);
        const v2f a = r[i0], b = r[i1];
        r[i0] = __builtin_elementwise_fma(vms, b, a * c);   // c*a - s*b
        r[i1] = __builtin_elementwise_fma(vps, a, b * c);   // s*a + c*b
    }
}

// RY via single-DPP partner exchange on a lane bit.
template<int CTRL>
__device__ __forceinline__ void ry_dpp(v2f* r, float c, v2f vsp) {
#pragma unroll
    for (int k = 0; k < 16; ++k) {
        const v2f p = { fdpp<CTRL>(r[k].x), fdpp<CTRL>(r[k].y) };
        r[k] = __builtin_elementwise_fma(vsp, p, r[k] * c);
    }
}

// RY on lane bit 2 (XOR4): partner = half_mirror(quad_xor3(x)) -> x[l^7^3] = x[l^4].
__device__ __forceinline__ void ry_xor4(v2f* r, float c, v2f vsp) {
#pragma unroll
    for (int k = 0; k < 16; ++k) {
        const v2f p = { fdpp<0x141>(fdpp<0x1B>(r[k].x)),
                        fdpp<0x141>(fdpp<0x1B>(r[k].y)) };
        r[k] = __builtin_elementwise_fma(vsp, p, r[k] * c);
    }
}

__global__ __launch_bounds__(TPB, 4)
void qmnist_kernel(const float* __restrict__ x,  const float* __restrict__ W1,
                   const float* __restrict__ b1, const float* __restrict__ ryp,
                   const float* __restrict__ rzp, const float* __restrict__ W2,
                   const float* __restrict__ b2, float* __restrict__ out) {
    // Exactly 32 KiB LDS. Small arrays alias the front (state lives in
    // registers whenever they are live; barriers order every transition).
    __shared__ v2f psi[DIM];
    float* smf  = (float*)psi;
    float* wred = smf;        // 48 floats
    float* encc = smf + 48;   // 12
    float* encs = smf + 60;   // 12
    float* zfin = smf + 72;   // 12

    const int tid  = threadIdx.x;
    const int blk  = blockIdx.x;
    const int lane = tid & 63;
    const int wave = tid >> 6;

    // ---------------- phase 0: feat = x[blk] @ W1^T + b1 -> encoding angles
    float acc[NW];
#pragma unroll
    for (int w = 0; w < NW; ++w) acc[w] = 0.f;
    if (tid < 196) {                      // 784 = 196 float4
        const float4 xv = ((const float4*)(x + (size_t)blk * 784))[tid];
#pragma unroll
        for (int w = 0; w < NW; ++w) {
            const float4 wv = ((const float4*)(W1 + w * 784))[tid];
            acc[w] = fmaf(xv.x, wv.x, fmaf(xv.y, wv.y, fmaf(xv.z, wv.z, xv.w * wv.w)));
        }
    }
#pragma unroll
    for (int w = 0; w < NW; ++w) {
        float v = acc[w];
        v += __shfl_down(v, 32);
        v += __shfl_down(v, 16);
        v += __shfl_down(v, 8);
        v += __shfl_down(v, 4);
        v += __shfl_down(v, 2);
        v += __shfl_down(v, 1);
        if (lane == 0) wred[wave * NW + w] = v;
    }
    __syncthreads();
    if (tid < NW) {
        float feat = wred[tid] + wred[NW + tid] + wred[2 * NW + tid] + wred[3 * NW + tid] + b1[tid];
        float a = tanhf(feat) * 3.14159265358979323846f;
        float h = 0.5f * a;
        encc[tid] = cosf(h);
        encs[tid] = sinf(h);
    }
    __syncthreads();

    // ---------------- init product state into REGISTERS.
    // amp index y = (k<<8)|tid; bit b of y <-> wire (11-b). bits 0..7 = tid, 8..11 = k.
    float hi = 1.f;
#pragma unroll
    for (int b = 0; b < 8; ++b)
        hi *= ((tid >> b) & 1) ? encs[11 - b] : encc[11 - b];
    v2f r[16];
#pragma unroll
    for (int k = 0; k < 16; ++k) {
        float f = hi;
        f *= (k & 1) ? encs[3] : encc[3];
        f *= (k & 2) ? encs[2] : encc[2];
        f *= (k & 4) ? encs[1] : encc[1];
        f *= (k & 8) ? encs[0] : encc[0];
        r[k] = (v2f){ f, 0.f };
    }

    // ---------------- variational params.
    // Layer = RY on all 12 positions, RZ on all 12 (folds to popcount phase,
    // layout-invariant), then CNOT staircase new[y] = old[y ^ (y>>1)].
    // Layer 3: RZ is a pure phase (|amp|^2 invariant) -> skipped; CNOT is
    // folded into the measurement signs (see measure phase).
    const float ry = ryp[0], rz = rzp[0];
    const float c = cosf(0.5f * ry), s = sinf(0.5f * ry);
    const v2f vps = {  s,  s };
    const v2f vms = { -s, -s };
    const int pcT = __popc(tid);
    // qv[j] = cis(rz*(pcT+j-6)), qp[j] = i*qv[j] — 2 sincos + complex
    // recurrence (numerics validated in the passing r9 run) instead of
    // 10 precise cosf/sinf per thread.
    v2f qv[5], qp[5];
    {
        float sb, cb; __sincosf(rz * (float)(pcT - 6), &sb, &cb);
        float sd, cd; __sincosf(rz, &sd, &cd);
        qv[0] = (v2f){ cb, sb };
        const v2f step = (v2f){ cd, sd };
#pragma unroll
        for (int j = 1; j < 5; ++j) qv[j] = cmulq(qv[j - 1], step);
#pragma unroll
        for (int j = 0; j < 5; ++j) qp[j] = (v2f){ -qv[j].y, qv[j].x };
    }

    // per-lane signed s (splat) for the DPP RY gates (position = lane bit 0..3)
    const v2f vs0 = (lane & 1) ? vps : vms;   // position 0, XOR1  quad_perm
    const v2f vs1 = (lane & 2) ? vps : vms;   // position 1, XOR2  quad_perm
    const v2f vs2 = (lane & 4) ? vps : vms;   // position 2, XOR4  chained DPP
    const v2f vs3 = (lane & 8) ? vps : vms;   // position 3, XOR8  row_ror:8

    // RT addressing (identity slot map; every access = ONE base + imm, and
    // slot low4 = t0..t3 (rank-4) on all four patterns -> conflict-free b64):
    //  RT-1 write : psi[(k<<8)|tid]           low4 = t0..3
    //  RT-1 read  : base_r | (k<<4)           low4 = t0..3   (k' = positions 4-7)
    //  RT-2 write : same slots as RT-1 read (same thread -> no barrier)
    //  RT-2 read  : (gt ^ (k&1)<<7) | gray4(k)<<8   low4 = Gray(t0..3)
    const int base_r = (tid & 15) | ((tid & 240) << 4);  // t0-3 + t4..7 -> slots 8..11
    const int gt     = tid ^ (tid >> 1);                 // Gray of tid (bit7 = t7)

    // ---------------- layers 0,1 (full: gates + RZ + CNOT gather)
    for (int layer = 0; layer < 2; ++layer) {
        __syncthreads();                // prior psi readers done

        // RY on positions 8-11 (reg bits), canonical layout
        ry_reg<0>(r, c, vps, vms); ry_reg<1>(r, c, vps, vms);
        ry_reg<2>(r, c, vps, vms); ry_reg<3>(r, c, vps, vms);

        // ---- RT-1: bring positions {4,5,6,7} into k'
#pragma unroll
        for (int k = 0; k < 16; ++k)
            psi[(k << 8) | tid] = r[k];
        __syncthreads();
#pragma unroll
        for (int k = 0; k < 16; ++k)
            r[k] = psi[base_r | (k << 4)];

        // positions 0-3 stay at lane bits through the swap: DPP gates here,
        // per-k independent -> overlaps the LDS read latency.
        ry_dpp<0xB1>(r, c, vs0);
        ry_dpp<0x4E>(r, c, vs1);
        ry_xor4(r, c, vs2);
        ry_dpp<0x128>(r, c, vs3);

        // gate positions 4,5,6,7 (now register bits 0-3)
        ry_reg<0>(r, c, vps, vms); ry_reg<1>(r, c, vps, vms);
        ry_reg<2>(r, c, vps, vms); ry_reg<3>(r, c, vps, vms);

        // fold of all 12 RZ gates: phase by popcount (position-invariant)
#pragma unroll
        for (int k = 0; k < 16; ++k) {
            const int j = __popc(k);    // compile-time per unrolled k
            r[k] = __builtin_elementwise_fma((v2f){ r[k].y, r[k].y }, qp[j], qv[j] * r[k].x);
        }

        // ---- RT-2: CNOT gather back to canonical layout.
        // Write slots == the slots THIS thread read in RT-1 (bijective) -> no
        // barrier; the storage map is the identity (slot == amp index).
#pragma unroll
        for (int k = 0; k < 16; ++k)
            psi[base_r | (k << 4)] = r[k];
        __syncthreads();
#pragma unroll
        for (int k = 0; k < 16; ++k) {
            const int gk = (k ^ (k >> 1)) & 15;
            r[k] = psi[(gt ^ ((k & 1) << 7)) | (gk << 8)];
        }
    }

    // ---------------- layer 2: gates only; RZ + CNOT folded into measurement
    __syncthreads();
    ry_reg<0>(r, c, vps, vms); ry_reg<1>(r, c, vps, vms);
    ry_reg<2>(r, c, vps, vms); ry_reg<3>(r, c, vps, vms);
#pragma unroll
    for (int k = 0; k < 16; ++k)
        psi[(k << 8) | tid] = r[k];
    __syncthreads();
#pragma unroll
    for (int k = 0; k < 16; ++k)
        r[k] = psi[base_r | (k << 4)];
    ry_dpp<0xB1>(r, c, vs0);
    ry_dpp<0x4E>(r, c, vs1);
    ry_xor4(r, c, vs2);
    ry_dpp<0x128>(r, c, vs3);
    ry_reg<0>(r, c, vps, vms); ry_reg<1>(r, c, vps, vms);
    ry_reg<2>(r, c, vps, vms); ry_reg<3>(r, c, vps, vms);
    __syncthreads();                    // all psi reads done before aliasing reuse

    // ---------------- measure <Z_w> with CNOT folded into signs.
    // State held: amp u = t0-3 | k<<4 | t4-7<<8 (pre-CNOT, phase-free modulus).
    // psi_post[v] = phi[v ^ (v>>1)]  =>  v_b = parity(u >> b), so
    // <Z_w> = sum_u (-1)^{parity(u >> (11-w))} |phi[u]|^2.
    float T = 0.f, Sp = 0.f, S1 = 0.f, S2 = 0.f, S3 = 0.f;
#pragma unroll
    for (int k = 0; k < 16; ++k) {
        const float pp = fmaf(r[k].x, r[k].x, r[k].y * r[k].y);
        T += pp;
        Sp += (__popc(k) & 1)        ? -pp : pp;   // parity(k)
        S1 += (__popc(k >> 1) & 1)   ? -pp : pp;   // parity(k>>1)
        S2 += (__popc(k >> 2) & 1)   ? -pp : pp;   // parity(k>>2)
        S3 += ((k >> 3) & 1)         ? -pp : pp;   // parity(k>>3)
    }
    const int t1 = (tid >> 1) & 1, t2 = (tid >> 2) & 1, t3 = (tid >> 3) & 1;
    const int t4 = (tid >> 4) & 1, t5 = (tid >> 5) & 1, t6 = (tid >> 6) & 1,
              t7 = (tid >> 7) & 1;
    const int p47 = t4 ^ t5 ^ t6 ^ t7;
    float contrib[NW];
    contrib[0]  = t7                   ? -T : T;    // b=11
    contrib[1]  = (t6 ^ t7)            ? -T : T;    // b=10
    contrib[2]  = (t5 ^ t6 ^ t7)       ? -T : T;    // b=9
    contrib[3]  = p47                  ? -T : T;    // b=8
    contrib[4]  = p47                  ? -S3 : S3;  // b=7
    contrib[5]  = p47                  ? -S2 : S2;  // b=6
    contrib[6]  = p47                  ? -S1 : S1;  // b=5
    contrib[7]  = p47                  ? -Sp : Sp;  // b=4
    contrib[8]  = (t3 ^ p47)           ? -Sp : Sp;  // b=3
    contrib[9]  = (t2 ^ t3 ^ p47)      ? -Sp : Sp;  // b=2
    contrib[10] = (t1 ^ t2 ^ t3 ^ p47) ? -Sp : Sp;  // b=1
    contrib[11] = (pcT & 1)            ? -Sp : Sp;  // b=0: parity(tid)
#pragma unroll
    for (int w = 0; w < NW; ++w) {
        float v = contrib[w];
        v += __shfl_down(v, 32);
        v += __shfl_down(v, 16);
        v += __shfl_down(v, 8);
        v += __shfl_down(v, 4);
        v += __shfl_down(v, 2);
        v += __shfl_down(v, 1);
        if (lane == 0) wred[wave * NW + w] = v;
    }
    __syncthreads();
    if (tid < NW)
        zfin[tid] = wred[tid] + wred[NW + tid] + wred[2 * NW + tid] + wred[3 * NW + tid];
    __syncthreads();

    // ---------------- head: out = z @ W2^T + b2
    if (tid < 10) {
        float o = b2[tid];
#pragma unroll
        for (int w = 0; w < NW; ++w)
            o = fmaf(zfin[w], W2[tid * NW + w], o);
        out[(size_t)blk * 10 + tid] = o;
    }
}

extern "C" void kernel_launch(void* const* d_in, const int* in_sizes, int n_in,
                              void* d_out, int out_size, void* d_ws, size_t ws_size,
                              hipStream_t stream) {
    const float* x   = (const float*)d_in[0];
    const float* W1  = (const float*)d_in[1];
    const float* b1  = (const float*)d_in[2];
    const float* ry  = (const float*)d_in[3];
    const float* rz  = (const float*)d_in[4];
    const float* W2  = (const float*)d_in[5];
    const float* b2  = (const float*)d_in[6];
    float* out = (float*)d_out;

    const int batch = in_sizes[0] / 784;   // 2048
    qmnist_kernel<<<batch, TPB, 0, stream>>>(x, W1, b1, ry, rz, W2, b2, out);
}

// Round 13
// 113.277 us; speedup vs baseline: 1.2355x; 1.0044x over previous
//
#include <hip/hip_runtime.h>
#include <math.h>

#define NW   12
#define DIM  4096
#define TPB  256

typedef float v2f __attribute__((ext_vector_type(2)));   // (re, im) -> v_pk_* f32

// DPP lane exchange (VALU, no LDS pipe).
// 0xB1=quad XOR1, 0x4E=quad XOR2, 0x1B=quad XOR3, 0x128=row_ror:8 (XOR8), 0x141=row_half_mirror (XOR7).
template<int CTRL>
__device__ __forceinline__ float fdpp(float v) {
    union { float f; int i; } u, w;
    u.f = v;
    w.i = __builtin_amdgcn_update_dpp(0, u.i, CTRL, 0xF, 0xF, false);
    return w.f;
}

__device__ __forceinline__ v2f cmulq(v2f a, v2f b) {
    return (v2f){ fmaf(a.x, b.x, -a.y * b.y), fmaf(a.x, b.y, a.y * b.x) };
}

// RY on register bit B (0..3 of the 16-amp register file). Packed-f32 VALU.
template<int B>
__device__ __forceinline__ void ry_reg(v2f* r, float c, v2f vps, v2f vms) {
#pragma unroll
    for (int p = 0; p < 8; ++p) {
        const int i0 = ((p >> B) << (B + 1)) | (p & ((1 << B) - 1));
        const int i1 = i0 | (1 << B);
        const v2f a = r[i0], b = r[i1];
        r[i0] = __builtin_elementwise_fma(vms, b, a * c);   // c*a - s*b
        r[i1] = __builtin_elementwise_fma(vps, a, b * c);   // s*a + c*b
    }
}

// RY via single-DPP partner exchange on a lane bit.
template<int CTRL>
__device__ __forceinline__ void ry_dpp(v2f* r, float c, v2f vsp) {
#pragma unroll
    for (int k = 0; k < 16; ++k) {
        const v2f p = { fdpp<CTRL>(r[k].x), fdpp<CTRL>(r[k].y) };
        r[k] = __builtin_elementwise_fma(vsp, p, r[k] * c);
    }
}

// RY on lane bit 2 (XOR4): partner = half_mirror(quad_xor3(x)) -> x[l^7^3] = x[l^4].
__device__ __forceinline__ void ry_xor4(v2f* r, float c, v2f vsp) {
#pragma unroll
    for (int k = 0; k < 16; ++k) {
        const v2f p = { fdpp<0x141>(fdpp<0x1B>(r[k].x)),
                        fdpp<0x141>(fdpp<0x1B>(r[k].y)) };
        r[k] = __builtin_elementwise_fma(vsp, p, r[k] * c);
    }
}

__global__ __launch_bounds__(TPB, 4)
void qmnist_kernel(const float* __restrict__ x,  const float* __restrict__ W1,
                   const float* __restrict__ b1, const float* __restrict__ ryp,
                   const float* __restrict__ rzp, const float* __restrict__ W2,
                   const float* __restrict__ b2, float* __restrict__ out) {
    // Exactly 32 KiB LDS. Small arrays alias the front (state lives in
    // registers whenever they are live; barriers order every transition).
    __shared__ v2f psi[DIM];
    float* smf  = (float*)psi;
    float* wred = smf;        // 48 floats
    float* encc = smf + 48;   // 12
    float* encs = smf + 60;   // 12
    float* zfin = smf + 72;   // 12

    const int tid  = threadIdx.x;
    const int blk  = blockIdx.x;
    const int lane = tid & 63;
    const int wave = tid >> 6;

    // ---------------- phase 0: feat = x[blk] @ W1^T + b1 -> encoding angles
    float acc[NW];
#pragma unroll
    for (int w = 0; w < NW; ++w) acc[w] = 0.f;
    if (tid < 196) {                      // 784 = 196 float4
        const float4 xv = ((const float4*)(x + (size_t)blk * 784))[tid];
#pragma unroll
        for (int w = 0; w < NW; ++w) {
            const float4 wv = ((const float4*)(W1 + w * 784))[tid];
            acc[w] = fmaf(xv.x, wv.x, fmaf(xv.y, wv.y, fmaf(xv.z, wv.z, xv.w * wv.w)));
        }
    }
#pragma unroll
    for (int w = 0; w < NW; ++w) {
        float v = acc[w];
        v += __shfl_down(v, 32);
        v += __shfl_down(v, 16);
        v += __shfl_down(v, 8);
        v += __shfl_down(v, 4);
        v += __shfl_down(v, 2);
        v += __shfl_down(v, 1);
        if (lane == 0) wred[wave * NW + w] = v;
    }
    __syncthreads();
    if (tid < NW) {
        float feat = wred[tid] + wred[NW + tid] + wred[2 * NW + tid] + wred[3 * NW + tid] + b1[tid];
        float a = tanhf(feat) * 3.14159265358979323846f;
        float h = 0.5f * a;
        encc[tid] = cosf(h);
        encs[tid] = sinf(h);
    }
    __syncthreads();

    // ---------------- init product state into REGISTERS.
    // amp index y = (k<<8)|tid; bit b of y <-> wire (11-b). bits 0..7 = tid, 8..11 = k.
    float hi = 1.f;
#pragma unroll
    for (int b = 0; b < 8; ++b)
        hi *= ((tid >> b) & 1) ? encs[11 - b] : encc[11 - b];
    v2f r[16];
#pragma unroll
    for (int k = 0; k < 16; ++k) {
        float f = hi;
        f *= (k & 1) ? encs[3] : encc[3];
        f *= (k & 2) ? encs[2] : encc[2];
        f *= (k & 4) ? encs[1] : encc[1];
        f *= (k & 8) ? encs[0] : encc[0];
        r[k] = (v2f){ f, 0.f };
    }

    // ---------------- variational params.
    const float ry = ryp[0], rz = rzp[0];
    const float c = cosf(0.5f * ry), s = sinf(0.5f * ry);
    const v2f vps = {  s,  s };
    const v2f vms = { -s, -s };
    const int pcT = __popc(tid);
    // qv[j] = cis(rz*(pcT+j-6)), qp[j] = i*qv[j] — 2 sincos + complex recurrence
    v2f qv[5], qp[5];
    {
        float sb, cb; __sincosf(rz * (float)(pcT - 6), &sb, &cb);
        float sd, cd; __sincosf(rz, &sd, &cd);
        qv[0] = (v2f){ cb, sb };
        const v2f step = (v2f){ cd, sd };
#pragma unroll
        for (int j = 1; j < 5; ++j) qv[j] = cmulq(qv[j - 1], step);
#pragma unroll
        for (int j = 0; j < 5; ++j) qp[j] = (v2f){ -qv[j].y, qv[j].x };
    }

    const v2f vs0 = (lane & 1) ? vps : vms;   // position 0, XOR1  quad_perm
    const v2f vs1 = (lane & 2) ? vps : vms;   // position 1, XOR2  quad_perm
    const v2f vs2 = (lane & 4) ? vps : vms;   // position 2, XOR4  chained DPP
    const v2f vs3 = (lane & 8) ? vps : vms;   // position 3, XOR8  row_ror:8

    // ---- Storage maps compose per layer via same-slot writes:
    //  sigma_0 = id, sigma_1 = Gray (y^(y>>1)), sigma_2 = Gray^2 (y^(y>>2)).
    // Every access = one base VGPR ^ compile-time imm; slot low4 is rank-4 in
    // t0..t3 for all patterns (triangular forms) -> conflict-free b64.
    const int A    = (tid & 15) | ((tid & 240) << 4);  // L1-amp base: t0-3 | t4-7<<8
    const int gt   = tid ^ (tid >> 1);                 // Gray(tid), bit7 = t7
    const int GA1  = A ^ (A >> 1);                     // Gray(A)
    const int GA2  = A ^ (A >> 2);                     // Gray^2(A)
    const int bs2  = tid ^ (tid >> 2);                 // Gray^2(tid), bits 0-7

    // macros over compile-time k (all inside #pragma unroll loops)
#define GREG() { ry_reg<0>(r, c, vps, vms); ry_reg<1>(r, c, vps, vms); \
                 ry_reg<2>(r, c, vps, vms); ry_reg<3>(r, c, vps, vms); }
#define GDPP() { ry_dpp<0xB1>(r, c, vs0); ry_dpp<0x4E>(r, c, vs1); \
                 ry_xor4(r, c, vs2);      ry_dpp<0x128>(r, c, vs3); }
#define RZF()  _Pragma("unroll") for (int k = 0; k < 16; ++k) { \
                 const int j = __popc(k); \
                 r[k] = __builtin_elementwise_fma((v2f){ r[k].y, r[k].y }, qp[j], qv[j] * r[k].x); }
    // sigma-dependent addresses (k compile-time):
#define S0_Y(k)   (((k) << 8) | tid)                                     // sigma0(y)
#define S0_A(k)   (A | ((k) << 4))                                       // sigma0(L1 amp)
#define S1_Y(k)   ((gt ^ (((k) & 1) << 7)) | ((((k) ^ ((k) >> 1)) & 15) << 8))  // sigma1(y) = Gray(y)
#define S1_A(k)   (GA1 ^ (((k) << 4) ^ ((k) << 3)))                      // sigma1(L1 amp)
#define S2_Y(k)   (bs2 ^ (((k) & 3) << 6) ^ ((((k) ^ ((k) >> 2)) & 15) << 8))   // sigma2(y)
#define S2_A(k)   (GA2 ^ (((k) << 4) ^ ((k) << 2)))                      // sigma2(L1 amp)

    // ================ layer 0 (sigma = id) ================
    __syncthreads();                    // init's enc reads done before psi writes
    GREG();                             // positions 8-11
#pragma unroll
    for (int k = 0; k < 16; ++k) psi[S0_Y(k)] = r[k];        // PW1_0
    __syncthreads();
#pragma unroll
    for (int k = 0; k < 16; ++k) r[k] = psi[S0_A(k)];        // PR1_0 -> L1 layout
    GDPP();                             // positions 0-3 (overlap LDS latency)
    GREG();                             // positions 4-7
    RZF();
#pragma unroll
    for (int k = 0; k < 16; ++k) psi[S0_A(k)] = r[k];        // PW2_0 (same-slot)
    __syncthreads();
#pragma unroll
    for (int k = 0; k < 16; ++k) r[k] = psi[S1_Y(k)];        // PR2_0: amp Gray(y) @ sigma0

    // ================ layer 1 (sigma = Gray) — no loop-top barrier:
    // PW1_1 writes exactly the slots THIS thread read in PR2_0 (bijective
    // partition; in-thread order via the r[k] data dependency).
    GREG();
#pragma unroll
    for (int k = 0; k < 16; ++k) psi[S1_Y(k)] = r[k];        // PW1_1 -> sigma1
    __syncthreads();
#pragma unroll
    for (int k = 0; k < 16; ++k) r[k] = psi[S1_A(k)];        // PR1_1
    GDPP();
    GREG();
    RZF();
#pragma unroll
    for (int k = 0; k < 16; ++k) psi[S1_A(k)] = r[k];        // PW2_1 (same-slot)
    __syncthreads();
#pragma unroll
    for (int k = 0; k < 16; ++k) r[k] = psi[S2_Y(k)];        // PR2_1: amp Gray(y) @ sigma1

    // ================ layer 2 (sigma = Gray^2; RZ+CNOT folded into measure)
    GREG();
#pragma unroll
    for (int k = 0; k < 16; ++k) psi[S2_Y(k)] = r[k];        // PW1_2 -> sigma2
    __syncthreads();
#pragma unroll
    for (int k = 0; k < 16; ++k) r[k] = psi[S2_A(k)];        // PR1_2 -> L1 layout
    GDPP();
    GREG();
    __syncthreads();                    // all psi reads done before aliasing reuse

    // ---------------- measure <Z_w> with CNOT folded into signs.
    // State held: amp u = t0-3 | k<<4 | t4-7<<8 (pre-CNOT, phase-free modulus).
    // psi_post[v] = phi[v ^ (v>>1)]  =>  <Z_w> sign = parity(u >> (11-w)).
    float T = 0.f, Sp = 0.f, S1 = 0.f, S2 = 0.f, S3 = 0.f;
#pragma unroll
    for (int k = 0; k < 16; ++k) {
        const float pp = fmaf(r[k].x, r[k].x, r[k].y * r[k].y);
        T += pp;
        Sp += (__popc(k) & 1)        ? -pp : pp;   // parity(k)
        S1 += (__popc(k >> 1) & 1)   ? -pp : pp;   // parity(k>>1)
        S2 += (__popc(k >> 2) & 1)   ? -pp : pp;   // parity(k>>2)
        S3 += ((k >> 3) & 1)         ? -pp : pp;   // parity(k>>3)
    }
    const int t1 = (tid >> 1) & 1, t2 = (tid >> 2) & 1, t3 = (tid >> 3) & 1;
    const int t4 = (tid >> 4) & 1, t5 = (tid >> 5) & 1, t6 = (tid >> 6) & 1,
              t7 = (tid >> 7) & 1;
    const int p47 = t4 ^ t5 ^ t6 ^ t7;
    float contrib[NW];
    contrib[0]  = t7                   ? -T : T;    // b=11
    contrib[1]  = (t6 ^ t7)            ? -T : T;    // b=10
    contrib[2]  = (t5 ^ t6 ^ t7)       ? -T : T;    // b=9
    contrib[3]  = p47                  ? -T : T;    // b=8
    contrib[4]  = p47                  ? -S3 : S3;  // b=7
    contrib[5]  = p47                  ? -S2 : S2;  // b=6
    contrib[6]  = p47                  ? -S1 : S1;  // b=5
    contrib[7]  = p47                  ? -Sp : Sp;  // b=4
    contrib[8]  = (t3 ^ p47)           ? -Sp : Sp;  // b=3
    contrib[9]  = (t2 ^ t3 ^ p47)      ? -Sp : Sp;  // b=2
    contrib[10] = (t1 ^ t2 ^ t3 ^ p47) ? -Sp : Sp;  // b=1
    contrib[11] = (pcT & 1)            ? -Sp : Sp;  // b=0: parity(tid)
#pragma unroll
    for (int w = 0; w < NW; ++w) {
        float v = contrib[w];
        v += __shfl_down(v, 32);
        v += __shfl_down(v, 16);
        v += __shfl_down(v, 8);
        v += __shfl_down(v, 4);
        v += __shfl_down(v, 2);
        v += __shfl_down(v, 1);
        if (lane == 0) wred[wave * NW + w] = v;
    }
    __syncthreads();
    if (tid < NW)
        zfin[tid] = wred[tid] + wred[NW + tid] + wred[2 * NW + tid] + wred[3 * NW + tid];
    __syncthreads();

    // ---------------- head: out = z @ W2^T + b2
    if (tid < 10) {
        float o = b2[tid];
#pragma unroll
        for (int w = 0; w < NW; ++w)
            o = fmaf(zfin[w], W2[tid * NW + w], o);
        out[(size_t)blk * 10 + tid] = o;
    }
}

extern "C" void kernel_launch(void* const* d_in, const int* in_sizes, int n_in,
                              void* d_out, int out_size, void* d_ws, size_t ws_size,
                              hipStream_t stream) {
    const float* x   = (const float*)d_in[0];
    const float* W1  = (const float*)d_in[1];
    const float* b1  = (const float*)d_in[2];
    const float* ry  = (const float*)d_in[3];
    const float* rz  = (const float*)d_in[4];
    const float* W2  = (const float*)d_in[5];
    const float* b2  = (const float*)d_in[6];
    float* out = (float*)d_out;

    const int batch = in_sizes[0] / 784;   // 2048
    qmnist_kernel<<<batch, TPB, 0, stream>>>(x, W1, b1, ry, rz, W2, b2, out);
}

// Round 14
// 110.532 us; speedup vs baseline: 1.2662x; 1.0248x over previous
//
#include <hip/hip_runtime.h>
#include <math.h>

#define NW   12
#define DIM  4096
#define TPB  256

typedef float v2f __attribute__((ext_vector_type(2)));   // (re, im) -> v_pk_* f32

// DPP lane exchange (VALU, no LDS pipe).
// 0xB1=quad XOR1, 0x4E=quad XOR2, 0x1B=quad XOR3, 0x128=row_ror:8 (XOR8), 0x141=row_half_mirror (XOR7).
template<int CTRL>
__device__ __forceinline__ float fdpp(float v) {
    union { float f; int i; } u, w;
    u.f = v;
    w.i = __builtin_amdgcn_update_dpp(0, u.i, CTRL, 0xF, 0xF, false);
    return w.f;
}

// DPP with bound_ctrl=1 (invalid lanes read 0) — for shift-based reductions.
template<int CTRL>
__device__ __forceinline__ float fdpp0(float v) {
    union { float f; int i; } u, w;
    u.f = v;
    w.i = __builtin_amdgcn_update_dpp(0, u.i, CTRL, 0xF, 0xF, true);
    return w.f;
}

// Full-wave sum via fused v_add_dpp: row_shr 1/2/4/8 then row_bcast 15/31.
// Result lands in lane 63. Zero LDS-pipe traffic (replaces 6 shfl_down).
__device__ __forceinline__ float wave_red(float v) {
    v += fdpp0<0x111>(v);   // row_shr:1
    v += fdpp0<0x112>(v);   // row_shr:2
    v += fdpp0<0x114>(v);   // row_shr:4
    v += fdpp0<0x118>(v);   // row_shr:8  -> lane15 of each row = row sum
    v += fdpp0<0x142>(v);   // row_bcast:15
    v += fdpp0<0x143>(v);   // row_bcast:31 -> lane 63 = wave sum
    return v;
}

__device__ __forceinline__ v2f cmulq(v2f a, v2f b) {
    return (v2f){ fmaf(a.x, b.x, -a.y * b.y), fmaf(a.x, b.y, a.y * b.x) };
}

// RY on register bit B (0..3 of the 16-amp register file). Packed-f32 VALU.
template<int B>
__device__ __forceinline__ void ry_reg(v2f* r, float c, v2f vps, v2f vms) {
#pragma unroll
    for (int p = 0; p < 8; ++p) {
        const int i0 = ((p >> B) << (B + 1)) | (p & ((1 << B) - 1));
        const int i1 = i0 | (1 << B);
        const v2f a = r[i0], b = r[i1];
        r[i0] = __builtin_elementwise_fma(vms, b, a * c);   // c*a - s*b
        r[i1] = __builtin_elementwise_fma(vps, a, b * c);   // s*a + c*b
    }
}

// RY via single-DPP partner exchange on a lane bit.
template<int CTRL>
__device__ __forceinline__ void ry_dpp(v2f* r, float c, v2f vsp) {
#pragma unroll
    for (int k = 0; k < 16; ++k) {
        const v2f p = { fdpp<CTRL>(r[k].x), fdpp<CTRL>(r[k].y) };
        r[k] = __builtin_elementwise_fma(vsp, p, r[k] * c);
    }
}

// RY on lane bit 2 (XOR4): partner = half_mirror(quad_xor3(x)) -> x[l^7^3] = x[l^4].
__device__ __forceinline__ void ry_xor4(v2f* r, float c, v2f vsp) {
#pragma unroll
    for (int k = 0; k < 16; ++k) {
        const v2f p = { fdpp<0x141>(fdpp<0x1B>(r[k].x)),
                        fdpp<0x141>(fdpp<0x1B>(r[k].y)) };
        r[k] = __builtin_elementwise_fma(vsp, p, r[k] * c);
    }
}

__global__ __launch_bounds__(TPB, 5)   // 5 blocks/CU: LDS 5x32KiB = 160KiB exact
void qmnist_kernel(const float* __restrict__ x,  const float* __restrict__ W1,
                   const float* __restrict__ b1, const float* __restrict__ ryp,
                   const float* __restrict__ rzp, const float* __restrict__ W2,
                   const float* __restrict__ b2, float* __restrict__ out) {
    // Exactly 32 KiB LDS. Small arrays alias the front (state lives in
    // registers whenever they are live; barriers order every transition).
    __shared__ v2f psi[DIM];
    float* smf  = (float*)psi;
    float* wred = smf;        // 48 floats
    float* encc = smf + 48;   // 12
    float* encs = smf + 60;   // 12
    float* zfin = smf + 72;   // 12

    const int tid  = threadIdx.x;
    const int blk  = blockIdx.x;
    const int lane = tid & 63;
    const int wave = tid >> 6;

    // ---------------- phase 0: feat = x[blk] @ W1^T + b1 -> encoding angles
    float acc[NW];
#pragma unroll
    for (int w = 0; w < NW; ++w) acc[w] = 0.f;
    if (tid < 196) {                      // 784 = 196 float4
        const float4 xv = ((const float4*)(x + (size_t)blk * 784))[tid];
#pragma unroll
        for (int w = 0; w < NW; ++w) {
            const float4 wv = ((const float4*)(W1 + w * 784))[tid];
            acc[w] = fmaf(xv.x, wv.x, fmaf(xv.y, wv.y, fmaf(xv.z, wv.z, xv.w * wv.w)));
        }
    }
#pragma unroll
    for (int w = 0; w < NW; ++w) {
        const float v = wave_red(acc[w]);
        if (lane == 63) wred[wave * NW + w] = v;
    }
    __syncthreads();
    if (tid < NW) {
        float feat = wred[tid] + wred[NW + tid] + wred[2 * NW + tid] + wred[3 * NW + tid] + b1[tid];
        float a = tanhf(feat) * 3.14159265358979323846f;
        float h = 0.5f * a;
        encc[tid] = cosf(h);
        encs[tid] = sinf(h);
    }
    __syncthreads();

    // ---------------- init product state into REGISTERS.
    // amp index y = (k<<8)|tid; bit b of y <-> wire (11-b). bits 0..7 = tid, 8..11 = k.
    float hi = 1.f;
#pragma unroll
    for (int b = 0; b < 8; ++b)
        hi *= ((tid >> b) & 1) ? encs[11 - b] : encc[11 - b];
    v2f r[16];
#pragma unroll
    for (int k = 0; k < 16; ++k) {
        float f = hi;
        f *= (k & 1) ? encs[3] : encc[3];
        f *= (k & 2) ? encs[2] : encc[2];
        f *= (k & 4) ? encs[1] : encc[1];
        f *= (k & 8) ? encs[0] : encc[0];
        r[k] = (v2f){ f, 0.f };
    }

    // ---------------- variational params.
    const float ry = ryp[0], rz = rzp[0];
    const float c = cosf(0.5f * ry), s = sinf(0.5f * ry);
    const v2f vps = {  s,  s };
    const v2f vms = { -s, -s };
    const int pcT = __popc(tid);
    // qv[j] = cis(rz*(pcT+j-6)), qp[j] = i*qv[j] — 2 sincos + complex recurrence
    v2f qv[5], qp[5];
    {
        float sb, cb; __sincosf(rz * (float)(pcT - 6), &sb, &cb);
        float sd, cd; __sincosf(rz, &sd, &cd);
        qv[0] = (v2f){ cb, sb };
        const v2f step = (v2f){ cd, sd };
#pragma unroll
        for (int j = 1; j < 5; ++j) qv[j] = cmulq(qv[j - 1], step);
#pragma unroll
        for (int j = 0; j < 5; ++j) qp[j] = (v2f){ -qv[j].y, qv[j].x };
    }

    const v2f vs0 = (lane & 1) ? vps : vms;   // position 0, XOR1  quad_perm
    const v2f vs1 = (lane & 2) ? vps : vms;   // position 1, XOR2  quad_perm
    const v2f vs2 = (lane & 4) ? vps : vms;   // position 2, XOR4  chained DPP
    const v2f vs3 = (lane & 8) ? vps : vms;   // position 3, XOR8  row_ror:8

    // ---- Storage maps compose per layer via same-slot writes:
    //  sigma_0 = id, sigma_1 = Gray (y^(y>>1)), sigma_2 = Gray^2 (y^(y>>2)).
    // Every access = one base VGPR ^ compile-time imm; slot low4 is rank-4 in
    // t0..t3 for all patterns (triangular forms) -> conflict-free b64.
    const int A    = (tid & 15) | ((tid & 240) << 4);  // L1-amp base: t0-3 | t4-7<<8
    const int gt   = tid ^ (tid >> 1);                 // Gray(tid), bit7 = t7
    const int GA1  = A ^ (A >> 1);                     // Gray(A)
    const int GA2  = A ^ (A >> 2);                     // Gray^2(A)
    const int bs2  = tid ^ (tid >> 2);                 // Gray^2(tid), bits 0-7

    // macros over compile-time k (all inside #pragma unroll loops)
#define GREG() { ry_reg<0>(r, c, vps, vms); ry_reg<1>(r, c, vps, vms); \
                 ry_reg<2>(r, c, vps, vms); ry_reg<3>(r, c, vps, vms); }
#define GDPP() { ry_dpp<0xB1>(r, c, vs0); ry_dpp<0x4E>(r, c, vs1); \
                 ry_xor4(r, c, vs2);      ry_dpp<0x128>(r, c, vs3); }
#define RZF()  _Pragma("unroll") for (int k = 0; k < 16; ++k) { \
                 const int j = __popc(k); \
                 r[k] = __builtin_elementwise_fma((v2f){ r[k].y, r[k].y }, qp[j], qv[j] * r[k].x); }
    // sigma-dependent addresses (k compile-time):
#define S0_Y(k)   (((k) << 8) | tid)                                     // sigma0(y)
#define S0_A(k)   (A | ((k) << 4))                                       // sigma0(L1 amp)
#define S1_Y(k)   ((gt ^ (((k) & 1) << 7)) | ((((k) ^ ((k) >> 1)) & 15) << 8))  // sigma1(y) = Gray(y)
#define S1_A(k)   (GA1 ^ (((k) << 4) ^ ((k) << 3)))                      // sigma1(L1 amp)
#define S2_Y(k)   (bs2 ^ (((k) & 3) << 6) ^ ((((k) ^ ((k) >> 2)) & 15) << 8))   // sigma2(y)
#define S2_A(k)   (GA2 ^ (((k) << 4) ^ ((k) << 2)))                      // sigma2(L1 amp)

    // ================ layer 0 (sigma = id) ================
    __syncthreads();                    // init's enc reads done before psi writes
    GREG();                             // positions 8-11
#pragma unroll
    for (int k = 0; k < 16; ++k) psi[S0_Y(k)] = r[k];        // PW1_0
    __syncthreads();
#pragma unroll
    for (int k = 0; k < 16; ++k) r[k] = psi[S0_A(k)];        // PR1_0 -> L1 layout
    GDPP();                             // positions 0-3 (overlap LDS latency)
    GREG();                             // positions 4-7
    RZF();
#pragma unroll
    for (int k = 0; k < 16; ++k) psi[S0_A(k)] = r[k];        // PW2_0 (same-slot)
    __syncthreads();
#pragma unroll
    for (int k = 0; k < 16; ++k) r[k] = psi[S1_Y(k)];        // PR2_0: amp Gray(y) @ sigma0

    // ================ layer 1 (sigma = Gray) — no loop-top barrier:
    // PW1_1 writes exactly the slots THIS thread read in PR2_0 (bijective
    // partition; in-thread order via the r[k] data dependency).
    GREG();
#pragma unroll
    for (int k = 0; k < 16; ++k) psi[S1_Y(k)] = r[k];        // PW1_1 -> sigma1
    __syncthreads();
#pragma unroll
    for (int k = 0; k < 16; ++k) r[k] = psi[S1_A(k)];        // PR1_1
    GDPP();
    GREG();
    RZF();
#pragma unroll
    for (int k = 0; k < 16; ++k) psi[S1_A(k)] = r[k];        // PW2_1 (same-slot)
    __syncthreads();
#pragma unroll
    for (int k = 0; k < 16; ++k) r[k] = psi[S2_Y(k)];        // PR2_1: amp Gray(y) @ sigma1

    // ================ layer 2 (sigma = Gray^2; RZ+CNOT folded into measure)
    GREG();
#pragma unroll
    for (int k = 0; k < 16; ++k) psi[S2_Y(k)] = r[k];        // PW1_2 -> sigma2
    __syncthreads();
#pragma unroll
    for (int k = 0; k < 16; ++k) r[k] = psi[S2_A(k)];        // PR1_2 -> L1 layout
    GDPP();
    GREG();
    __syncthreads();                    // all psi reads done before aliasing reuse

    // ---------------- measure <Z_w> with CNOT folded into signs.
    // State held: amp u = t0-3 | k<<4 | t4-7<<8 (pre-CNOT, phase-free modulus).
    // psi_post[v] = phi[v ^ (v>>1)]  =>  <Z_w> sign = parity(u >> (11-w)).
    float T = 0.f, Sp = 0.f, S1 = 0.f, S2 = 0.f, S3 = 0.f;
#pragma unroll
    for (int k = 0; k < 16; ++k) {
        const float pp = fmaf(r[k].x, r[k].x, r[k].y * r[k].y);
        T += pp;
        Sp += (__popc(k) & 1)        ? -pp : pp;   // parity(k)
        S1 += (__popc(k >> 1) & 1)   ? -pp : pp;   // parity(k>>1)
        S2 += (__popc(k >> 2) & 1)   ? -pp : pp;   // parity(k>>2)
        S3 += ((k >> 3) & 1)         ? -pp : pp;   // parity(k>>3)
    }
    const int t1 = (tid >> 1) & 1, t2 = (tid >> 2) & 1, t3 = (tid >> 3) & 1;
    const int t4 = (tid >> 4) & 1, t5 = (tid >> 5) & 1, t6 = (tid >> 6) & 1,
              t7 = (tid >> 7) & 1;
    const int p47 = t4 ^ t5 ^ t6 ^ t7;
    float contrib[NW];
    contrib[0]  = t7                   ? -T : T;    // b=11
    contrib[1]  = (t6 ^ t7)            ? -T : T;    // b=10
    contrib[2]  = (t5 ^ t6 ^ t7)       ? -T : T;    // b=9
    contrib[3]  = p47                  ? -T : T;    // b=8
    contrib[4]  = p47                  ? -S3 : S3;  // b=7
    contrib[5]  = p47                  ? -S2 : S2;  // b=6
    contrib[6]  = p47                  ? -S1 : S1;  // b=5
    contrib[7]  = p47                  ? -Sp : Sp;  // b=4
    contrib[8]  = (t3 ^ p47)           ? -Sp : Sp;  // b=3
    contrib[9]  = (t2 ^ t3 ^ p47)      ? -Sp : Sp;  // b=2
    contrib[10] = (t1 ^ t2 ^ t3 ^ p47) ? -Sp : Sp;  // b=1
    contrib[11] = (pcT & 1)            ? -Sp : Sp;  // b=0: parity(tid)
#pragma unroll
    for (int w = 0; w < NW; ++w) {
        const float v = wave_red(contrib[w]);
        if (lane == 63) wred[wave * NW + w] = v;
    }
    __syncthreads();
    if (tid < NW)
        zfin[tid] = wred[tid] + wred[NW + tid] + wred[2 * NW + tid] + wred[3 * NW + tid];
    __syncthreads();

    // ---------------- head: out = z @ W2^T + b2
    if (tid < 10) {
        float o = b2[tid];
#pragma unroll
        for (int w = 0; w < NW; ++w)
            o = fmaf(zfin[w], W2[tid * NW + w], o);
        out[(size_t)blk * 10 + tid] = o;
    }
}

extern "C" void kernel_launch(void* const* d_in, const int* in_sizes, int n_in,
                              void* d_out, int out_size, void* d_ws, size_t ws_size,
                              hipStream_t stream) {
    const float* x   = (const float*)d_in[0];
    const float* W1  = (const float*)d_in[1];
    const float* b1  = (const float*)d_in[2];
    const float* ry  = (const float*)d_in[3];
    const float* rz  = (const float*)d_in[4];
    const float* W2  = (const float*)d_in[5];
    const float* b2  = (const float*)d_in[6];
    float* out = (float*)d_out;

    const int batch = in_sizes[0] / 784;   // 2048
    qmnist_kernel<<<batch, TPB, 0, stream>>>(x, W1, b1, ry, rz, W2, b2, out);
}